// Round 1
// baseline (12009.883 us; speedup 1.0000x reference)
//
#include <hip/hip_runtime.h>
#include <math.h>

#define TILE 64
#define KSTEP 16

// C[M,N] = A[M,K] @ B[K,N], fp32, 64x64 tile, 4x4 per-thread micro-tile.
__global__ __launch_bounds__(256) void gemm_tile(const float* __restrict__ A,
                                                 const float* __restrict__ B,
                                                 float* __restrict__ C,
                                                 int M, int N, int K) {
    __shared__ float As[KSTEP][TILE + 4];  // transposed: As[k][m]; +4 pad keeps 16B align, breaks conflicts
    __shared__ float Bs[KSTEP][TILE];

    const int tid = threadIdx.x;        // 0..255
    const int tx = tid & 15;            // col group
    const int ty = tid >> 4;            // row group (0..15)
    const int row0 = blockIdx.x * TILE;
    const int col0 = blockIdx.y * TILE;

    float acc[4][4] = {};

    for (int k0 = 0; k0 < K; k0 += KSTEP) {
        // A tile: 64 rows x 16 k. thread t: k = t%16, r = t/16 + i*16
        {
            const int k = tid & 15;
            const int r = tid >> 4;
            #pragma unroll
            for (int i = 0; i < 4; ++i) {
                const int rr = r + i * 16;
                const int grow = row0 + rr;
                float v = 0.0f;
                if (grow < M) v = A[(size_t)grow * K + k0 + k];
                As[k][rr] = v;
            }
        }
        // B tile: 16 k x 64 cols. thread t: c = t%64, kk = t/64 + i*4
        {
            const int c = tid & 63;
            const int kb = tid >> 6;
            #pragma unroll
            for (int i = 0; i < 4; ++i) {
                const int kk = kb + i * 4;
                Bs[kk][c] = B[(size_t)(k0 + kk) * N + col0 + c];
            }
        }
        __syncthreads();
        #pragma unroll
        for (int kk = 0; kk < KSTEP; ++kk) {
            const float4 a4 = *(const float4*)&As[kk][ty * 4];
            const float4 b4 = *(const float4*)&Bs[kk][tx * 4];
            const float av[4] = {a4.x, a4.y, a4.z, a4.w};
            const float bv[4] = {b4.x, b4.y, b4.z, b4.w};
            #pragma unroll
            for (int i = 0; i < 4; ++i)
                #pragma unroll
                for (int j = 0; j < 4; ++j)
                    acc[i][j] += av[i] * bv[j];
        }
        __syncthreads();
    }

    #pragma unroll
    for (int i = 0; i < 4; ++i) {
        const int r = row0 + ty * 4 + i;
        if (r < M) {
            float4 v = make_float4(acc[i][0], acc[i][1], acc[i][2], acc[i][3]);
            *(float4*)&C[(size_t)r * N + col0 + tx * 4] = v;
        }
    }
}

// y[row] += val * X[col]  for each edge; F=256, one wave per edge, float4/lane.
__global__ __launch_bounds__(256) void spmm256(const int* __restrict__ rows,
                                               const int* __restrict__ cols,
                                               const float* __restrict__ vals,
                                               const float* __restrict__ X,
                                               float* __restrict__ Y, int E) {
    const int wid = blockIdx.x * 4 + (threadIdx.x >> 6);
    if (wid >= E) return;
    const int lane = threadIdx.x & 63;
    const int r = rows[wid];
    const int c = cols[wid];
    const float v = vals[wid];
    const float4 xv = ((const float4*)(X + (size_t)c * 256))[lane];
    float* yp = Y + (size_t)r * 256 + lane * 4;
    atomicAdd(yp + 0, v * xv.x);
    atomicAdd(yp + 1, v * xv.y);
    atomicAdd(yp + 2, v * xv.z);
    atomicAdd(yp + 3, v * xv.w);
}

// F=64 variant: one wave per edge, one float per lane.
__global__ __launch_bounds__(256) void spmm64(const int* __restrict__ rows,
                                              const int* __restrict__ cols,
                                              const float* __restrict__ vals,
                                              const float* __restrict__ X,
                                              float* __restrict__ Y, int E) {
    const int wid = blockIdx.x * 4 + (threadIdx.x >> 6);
    if (wid >= E) return;
    const int lane = threadIdx.x & 63;
    const int r = rows[wid];
    const int c = cols[wid];
    const float v = vals[wid];
    const float xv = X[(size_t)c * 64 + lane];
    atomicAdd(Y + (size_t)r * 64 + lane, v * xv);
}

__global__ __launch_bounds__(256) void bias_relu(float* __restrict__ y,
                                                 const float* __restrict__ b,
                                                 int n, int Fmask) {
    const int i = blockIdx.x * blockDim.x + threadIdx.x;
    if (i < n) {
        const float v = y[i] + b[i & Fmask];
        y[i] = v > 0.0f ? v : 0.0f;
    }
}

// in-place: Y[row] = log_softmax(Y[row] + b), row length 64, one wave per row.
__global__ __launch_bounds__(256) void bias_logsoftmax(float* __restrict__ Y,
                                                       const float* __restrict__ b,
                                                       int n) {
    const int row = blockIdx.x * 4 + (threadIdx.x >> 6);
    if (row >= n) return;
    const int lane = threadIdx.x & 63;
    const float v = Y[(size_t)row * 64 + lane] + b[lane];
    float m = v;
    #pragma unroll
    for (int o = 32; o > 0; o >>= 1) m = fmaxf(m, __shfl_xor(m, o));
    const float e = __expf(v - m);
    float s = e;
    #pragma unroll
    for (int o = 32; o > 0; o >>= 1) s += __shfl_xor(s, o);
    Y[(size_t)row * 64 + lane] = v - m - __logf(s);
}

extern "C" void kernel_launch(void* const* d_in, const int* in_sizes, int n_in,
                              void* d_out, int out_size, void* d_ws, size_t ws_size,
                              hipStream_t stream) {
    const float* x    = (const float*)d_in[0];
    const int*   erow = (const int*)d_in[1];
    const int*   ecol = (const int*)d_in[2];
    const float* eval = (const float*)d_in[3];
    const float* W1   = (const float*)d_in[4];
    const float* b1   = (const float*)d_in[5];
    const float* W2   = (const float*)d_in[6];
    const float* b2   = (const float*)d_in[7];
    float* out = (float*)d_out;

    const int E      = in_sizes[1];
    const int nhid   = in_sizes[5];              // 256
    const int nclass = in_sizes[7];              // 64
    const int nfeat  = in_sizes[4] / nhid;       // 512
    const int N      = in_sizes[0] / nfeat;      // 100000

    float* h0 = (float*)d_ws;                    // N*nhid fp32 (x@W1, then reused for h@W2)
    float* h1 = h0 + (size_t)N * nhid;           // N*nhid fp32 (aggregation / relu output)

    hipMemsetAsync(h1, 0, (size_t)N * nhid * sizeof(float), stream);
    hipMemsetAsync(out, 0, (size_t)N * nclass * sizeof(float), stream);

    // layer 1: h0 = x @ W1
    dim3 g1((N + TILE - 1) / TILE, nhid / TILE);
    gemm_tile<<<g1, 256, 0, stream>>>(x, W1, h0, N, nhid, nfeat);
    // h1 = spmm(h0)
    spmm256<<<(E + 3) / 4, 256, 0, stream>>>(erow, ecol, eval, h0, h1, E);
    // h1 = relu(h1 + b1)
    const int tot1 = N * nhid;
    bias_relu<<<(tot1 + 255) / 256, 256, 0, stream>>>(h1, b1, tot1, nhid - 1);

    // layer 2: h0 = h1 @ W2  (N x nclass)
    dim3 g2((N + TILE - 1) / TILE, nclass / TILE);
    gemm_tile<<<g2, 256, 0, stream>>>(h1, W2, h0, N, nclass, nhid);
    // out = spmm(h0)
    spmm64<<<(E + 3) / 4, 256, 0, stream>>>(erow, ecol, eval, h0, out, E);
    // out = log_softmax(out + b2)
    bias_logsoftmax<<<(N + 3) / 4, 256, 0, stream>>>(out, b2, N);
}

// Round 2
// 1368.108 us; speedup vs baseline: 8.7785x; 8.7785x over previous
//
#include <hip/hip_runtime.h>
#include <math.h>

#define TILE 64
#define KSTEP 16
#define SCAN_CHUNK 2048

__device__ __forceinline__ float bf2f(unsigned short u) {
    return __uint_as_float(((unsigned)u) << 16);
}
__device__ __forceinline__ unsigned short f2bf(float f) {
    unsigned u = __float_as_uint(f);
    unsigned r = u + 0x7FFF + ((u >> 16) & 1);   // RNE
    return (unsigned short)(r >> 16);
}

// C[M,N] = A[M,K] @ B[K,N], fp32 in; out fp32 or bf16.
template <bool BF16OUT>
__global__ __launch_bounds__(256) void gemm_tile(const float* __restrict__ A,
                                                 const float* __restrict__ B,
                                                 void* __restrict__ Cv,
                                                 int M, int N, int K) {
    __shared__ float As[KSTEP][TILE + 4];
    __shared__ float Bs[KSTEP][TILE];

    const int tid = threadIdx.x;
    const int tx = tid & 15;
    const int ty = tid >> 4;
    const int row0 = blockIdx.x * TILE;
    const int col0 = blockIdx.y * TILE;

    float acc[4][4] = {};

    for (int k0 = 0; k0 < K; k0 += KSTEP) {
        {
            const int k = tid & 15;
            const int r = tid >> 4;
            #pragma unroll
            for (int i = 0; i < 4; ++i) {
                const int rr = r + i * 16;
                const int grow = row0 + rr;
                float v = 0.0f;
                if (grow < M) v = A[(size_t)grow * K + k0 + k];
                As[k][rr] = v;
            }
        }
        {
            const int c = tid & 63;
            const int kb = tid >> 6;
            #pragma unroll
            for (int i = 0; i < 4; ++i) {
                const int kk = kb + i * 4;
                Bs[kk][c] = B[(size_t)(k0 + kk) * N + col0 + c];
            }
        }
        __syncthreads();
        #pragma unroll
        for (int kk = 0; kk < KSTEP; ++kk) {
            const float4 a4 = *(const float4*)&As[kk][ty * 4];
            const float4 b4 = *(const float4*)&Bs[kk][tx * 4];
            const float av[4] = {a4.x, a4.y, a4.z, a4.w};
            const float bv[4] = {b4.x, b4.y, b4.z, b4.w};
            #pragma unroll
            for (int i = 0; i < 4; ++i)
                #pragma unroll
                for (int j = 0; j < 4; ++j)
                    acc[i][j] += av[i] * bv[j];
        }
        __syncthreads();
    }

    #pragma unroll
    for (int i = 0; i < 4; ++i) {
        const int r = row0 + ty * 4 + i;
        if (r < M) {
            if constexpr (BF16OUT) {
                ushort4 o;
                o.x = f2bf(acc[i][0]); o.y = f2bf(acc[i][1]);
                o.z = f2bf(acc[i][2]); o.w = f2bf(acc[i][3]);
                *(ushort4*)((unsigned short*)Cv + (size_t)r * N + col0 + tx * 4) = o;
            } else {
                *(float4*)((float*)Cv + (size_t)r * N + col0 + tx * 4) =
                    make_float4(acc[i][0], acc[i][1], acc[i][2], acc[i][3]);
            }
        }
    }
}

// ---- CSR build ----
__global__ __launch_bounds__(256) void hist_rows(const int* __restrict__ rows,
                                                 int* __restrict__ cnt, int E) {
    const int i = blockIdx.x * 256 + threadIdx.x;
    if (i < E) atomicAdd(&cnt[rows[i]], 1);
}

// exclusive scan, in-place safe (each thread reads its 8 before writing).
__global__ __launch_bounds__(256) void scan_pass1(const int* __restrict__ in,
                                                  int* __restrict__ out,
                                                  int* __restrict__ bsum, int n) {
    const int t = threadIdx.x;
    const int base = blockIdx.x * SCAN_CHUNK + t * 8;
    int v[8];
    int s = 0;
    #pragma unroll
    for (int i = 0; i < 8; ++i) {
        const int idx = base + i;
        v[i] = (idx < n) ? in[idx] : 0;
        s += v[i];
    }
    const int lane = t & 63;
    const int wid = t >> 6;
    int incl = s;
    #pragma unroll
    for (int o = 1; o < 64; o <<= 1) {
        int y = __shfl_up(incl, o);
        if (lane >= o) incl += y;
    }
    __shared__ int wsum[4];
    if (lane == 63) wsum[wid] = incl;
    __syncthreads();
    int woff = 0;
    for (int w = 0; w < wid; ++w) woff += wsum[w];
    int run = woff + incl - s;  // exclusive prefix for this thread's first elem
    #pragma unroll
    for (int i = 0; i < 8; ++i) {
        const int idx = base + i;
        if (idx < n) out[idx] = run;
        run += v[i];
    }
    if (t == 255) bsum[blockIdx.x] = woff + incl;
}

__global__ void scan_pass2(int* __restrict__ bsum, int nb) {
    const int t = threadIdx.x;  // 64 threads
    int carry = 0;
    for (int start = 0; start < nb; start += 64) {
        const int i = start + t;
        int v = (i < nb) ? bsum[i] : 0;
        int incl = v;
        #pragma unroll
        for (int o = 1; o < 64; o <<= 1) {
            int y = __shfl_up(incl, o);
            if (t >= o) incl += y;
        }
        if (i < nb) bsum[i] = carry + incl - v;
        carry += __shfl(incl, 63);
    }
}

__global__ __launch_bounds__(256) void scan_pass3(int* __restrict__ out,
                                                  const int* __restrict__ bsum, int n) {
    const int i = blockIdx.x * 256 + threadIdx.x;
    if (i < n) out[i] += bsum[i / SCAN_CHUNK];
}

__global__ __launch_bounds__(256) void scatter_edges(const int* __restrict__ rows,
                                                     const int* __restrict__ cols,
                                                     const float* __restrict__ vals,
                                                     const int* __restrict__ rs,
                                                     int* __restrict__ cursor,
                                                     int2* __restrict__ edges, int E) {
    const int e = blockIdx.x * 256 + threadIdx.x;
    if (e >= E) return;
    const int r = rows[e];
    const int pos = rs[r] + atomicAdd(&cursor[r], 1);
    edges[pos] = make_int2(cols[e], __float_as_int(vals[e]));
}

// ---- CSR spmm, one wave per row ----
// F=256 (bf16 X), fused bias+relu, fp32 out.
__global__ __launch_bounds__(256) void spmm_csr256_relu(const int2* __restrict__ edges,
                                                        const int* __restrict__ rs,
                                                        const unsigned short* __restrict__ X,
                                                        const float* __restrict__ bias,
                                                        float* __restrict__ Y, int N) {
    const int row = blockIdx.x * 4 + (threadIdx.x >> 6);
    if (row >= N) return;
    const int lane = threadIdx.x & 63;
    const int s = rs[row], e = rs[row + 1];
    float a0 = 0.f, a1 = 0.f, a2 = 0.f, a3 = 0.f;
    int i = s;
    for (; i + 1 < e; i += 2) {
        const int2 e0 = edges[i];
        const int2 e1 = edges[i + 1];
        const ushort4 x0 = ((const ushort4*)(X + (size_t)e0.x * 256))[lane];
        const ushort4 x1 = ((const ushort4*)(X + (size_t)e1.x * 256))[lane];
        const float v0 = __int_as_float(e0.y);
        const float v1 = __int_as_float(e1.y);
        a0 += v0 * bf2f(x0.x) + v1 * bf2f(x1.x);
        a1 += v0 * bf2f(x0.y) + v1 * bf2f(x1.y);
        a2 += v0 * bf2f(x0.z) + v1 * bf2f(x1.z);
        a3 += v0 * bf2f(x0.w) + v1 * bf2f(x1.w);
    }
    if (i < e) {
        const int2 e0 = edges[i];
        const ushort4 x0 = ((const ushort4*)(X + (size_t)e0.x * 256))[lane];
        const float v0 = __int_as_float(e0.y);
        a0 += v0 * bf2f(x0.x);
        a1 += v0 * bf2f(x0.y);
        a2 += v0 * bf2f(x0.z);
        a3 += v0 * bf2f(x0.w);
    }
    const float4 bb = ((const float4*)bias)[lane];
    a0 = fmaxf(a0 + bb.x, 0.f);
    a1 = fmaxf(a1 + bb.y, 0.f);
    a2 = fmaxf(a2 + bb.z, 0.f);
    a3 = fmaxf(a3 + bb.w, 0.f);
    ((float4*)(Y + (size_t)row * 256))[lane] = make_float4(a0, a1, a2, a3);
}

// F=64 (fp32 X), fused bias + log_softmax.
__global__ __launch_bounds__(256) void spmm_csr64_lsm(const int2* __restrict__ edges,
                                                      const int* __restrict__ rs,
                                                      const float* __restrict__ X,
                                                      const float* __restrict__ bias,
                                                      float* __restrict__ out, int N) {
    const int row = blockIdx.x * 4 + (threadIdx.x >> 6);
    if (row >= N) return;
    const int lane = threadIdx.x & 63;
    const int s = rs[row], e = rs[row + 1];
    float acc = 0.f;
    int i = s;
    for (; i + 1 < e; i += 2) {
        const int2 e0 = edges[i];
        const int2 e1 = edges[i + 1];
        acc += __int_as_float(e0.y) * X[(size_t)e0.x * 64 + lane]
             + __int_as_float(e1.y) * X[(size_t)e1.x * 64 + lane];
    }
    if (i < e) {
        const int2 e0 = edges[i];
        acc += __int_as_float(e0.y) * X[(size_t)e0.x * 64 + lane];
    }
    float v = acc + bias[lane];
    float m = v;
    #pragma unroll
    for (int o = 32; o; o >>= 1) m = fmaxf(m, __shfl_xor(m, o));
    const float ex = __expf(v - m);
    float ssum = ex;
    #pragma unroll
    for (int o = 32; o; o >>= 1) ssum += __shfl_xor(ssum, o);
    out[(size_t)row * 64 + lane] = v - m - __logf(ssum);
}

extern "C" void kernel_launch(void* const* d_in, const int* in_sizes, int n_in,
                              void* d_out, int out_size, void* d_ws, size_t ws_size,
                              hipStream_t stream) {
    const float* x    = (const float*)d_in[0];
    const int*   erow = (const int*)d_in[1];
    const int*   ecol = (const int*)d_in[2];
    const float* eval = (const float*)d_in[3];
    const float* W1   = (const float*)d_in[4];
    const float* b1   = (const float*)d_in[5];
    const float* W2   = (const float*)d_in[6];
    const float* b2   = (const float*)d_in[7];
    float* out = (float*)d_out;

    const int E      = in_sizes[1];
    const int nhid   = in_sizes[5];              // 256
    const int nclass = in_sizes[7];              // 64
    const int nfeat  = in_sizes[4] / nhid;       // 512
    const int N      = in_sizes[0] / nfeat;      // 100000

    // workspace layout (~180 MB)
    char* w = (char*)d_ws;
    float* h1 = (float*)w;                         w += (size_t)N * nhid * 4;   // relu out, fp32
    unsigned short* h0bf = (unsigned short*)w;     // gemm1 out, bf16 (N*nhid)
    float* h2 = (float*)h0bf;                      // gemm2 out aliases (h0bf dead by then)
    w += (size_t)N * nhid * 2;
    int2* edges = (int2*)w;                        w += (size_t)E * 8;
    int* rs = (int*)w;                             w += (size_t)(N + 1) * 4;
    int* cursor = (int*)w;                         w += (size_t)N * 4;
    int* bsum = (int*)w;                           w += 64 * 4;

    const int nScan = N + 1;
    const int nbScan = (nScan + SCAN_CHUNK - 1) / SCAN_CHUNK;

    hipMemsetAsync(rs, 0, (size_t)(N + 1) * sizeof(int), stream);
    hipMemsetAsync(cursor, 0, (size_t)N * sizeof(int), stream);

    // CSR build (shared by both spmm layers)
    hist_rows<<<(E + 255) / 256, 256, 0, stream>>>(erow, rs, E);
    scan_pass1<<<nbScan, 256, 0, stream>>>(rs, rs, bsum, nScan);
    scan_pass2<<<1, 64, 0, stream>>>(bsum, nbScan);
    scan_pass3<<<(nScan + 255) / 256, 256, 0, stream>>>(rs, bsum, nScan);
    scatter_edges<<<(E + 255) / 256, 256, 0, stream>>>(erow, ecol, eval, rs, cursor, edges, E);

    // layer 1
    dim3 g1((N + TILE - 1) / TILE, nhid / TILE);
    gemm_tile<true><<<g1, 256, 0, stream>>>(x, W1, h0bf, N, nhid, nfeat);
    spmm_csr256_relu<<<(N + 3) / 4, 256, 0, stream>>>(edges, rs, h0bf, b1, h1, N);

    // layer 2
    dim3 g2((N + TILE - 1) / TILE, nclass / TILE);
    gemm_tile<false><<<g2, 256, 0, stream>>>(h1, W2, h2, N, nclass, nhid);
    spmm_csr64_lsm<<<(N + 3) / 4, 256, 0, stream>>>(edges, rs, h2, b2, out, N);
}

// Round 3
// 1096.599 us; speedup vs baseline: 10.9519x; 1.2476x over previous
//
#include <hip/hip_runtime.h>
#include <math.h>

#define SCAN_CHUNK 2048

typedef short bf16x8 __attribute__((ext_vector_type(8)));
typedef float f32x4 __attribute__((ext_vector_type(4)));

__device__ __forceinline__ float bf2f(unsigned short u) {
    return __uint_as_float(((unsigned)u) << 16);
}
__device__ __forceinline__ unsigned short f2bf(float f) {
    unsigned u = __float_as_uint(f);
    unsigned r = u + 0x7FFF + ((u >> 16) & 1);   // RNE
    return (unsigned short)(r >> 16);
}

#define GLD_LDS16(gp, lp)                                                     \
    __builtin_amdgcn_global_load_lds(                                         \
        (const __attribute__((address_space(1))) void*)(gp),                  \
        (__attribute__((address_space(3))) void*)(lp), 16, 0, 0)

// C[M,Ncols] = A[M,K](bf16) @ BT[Ncols,K](bf16)^T, fp32 acc via MFMA.
// Block tile BM x BN, 4 waves in 2x2; wave tile (BM/2)x(BN/2) of 16x16x32 mfma.
template <int BM, int BN, bool OUTBF16>
__global__ __launch_bounds__(256) void gemm_mfma(const unsigned short* __restrict__ A,
                                                 const unsigned short* __restrict__ BT,
                                                 void* __restrict__ Cv,
                                                 int M, int Ncols, int K) {
    constexpr int WM = BM / 2, WN = BN / 2, TM = WM / 16, TN = WN / 16;
    __shared__ unsigned short Al[BM * 32];
    __shared__ unsigned short Bl[BN * 32];

    const int tid = threadIdx.x;
    const int w = tid >> 6, lane = tid & 63;
    const int wm = w >> 1, wn = w & 1;
    const int row0 = blockIdx.x * BM, col0 = blockIdx.y * BN;
    const int q = lane >> 4, r = lane & 15;

    f32x4 acc[TM][TN];
    #pragma unroll
    for (int mt = 0; mt < TM; ++mt)
        #pragma unroll
        for (int nt = 0; nt < TN; ++nt) {
            f32x4 z = {0.f, 0.f, 0.f, 0.f};
            acc[mt][nt] = z;
        }

    for (int k0 = 0; k0 < K; k0 += 32) {
        __syncthreads();
        // stage A tile: BM rows x 32 k (64 B/row = 4 x 16B chunks)
        #pragma unroll
        for (int i = 0; i < BM / 64; ++i) {
            const int idx = i * 256 + tid;
            const int arow = idx >> 2, ch = idx & 3;
            int grow = row0 + arow;
            if (grow >= M) grow = M - 1;
            GLD_LDS16(A + (size_t)grow * K + k0 + ch * 8,
                      Al + (size_t)(i * 256 + w * 64) * 8);
        }
        // stage BT tile: BN rows x 32 k
        #pragma unroll
        for (int i = 0; i < BN / 64; ++i) {
            const int idx = i * 256 + tid;
            const int brow = idx >> 2, ch = idx & 3;
            GLD_LDS16(BT + (size_t)(col0 + brow) * K + k0 + ch * 8,
                      Bl + (size_t)(i * 256 + w * 64) * 8);
        }
        asm volatile("s_waitcnt vmcnt(0)" ::: "memory");
        __syncthreads();

        bf16x8 af[TM], bfr[TN];
        #pragma unroll
        for (int mt = 0; mt < TM; ++mt)
            af[mt] = *(const bf16x8*)&Al[(wm * WM + mt * 16 + r) * 32 + q * 8];
        #pragma unroll
        for (int nt = 0; nt < TN; ++nt)
            bfr[nt] = *(const bf16x8*)&Bl[(wn * WN + nt * 16 + r) * 32 + q * 8];
        #pragma unroll
        for (int mt = 0; mt < TM; ++mt)
            #pragma unroll
            for (int nt = 0; nt < TN; ++nt)
                acc[mt][nt] = __builtin_amdgcn_mfma_f32_16x16x32_bf16(
                    af[mt], bfr[nt], acc[mt][nt], 0, 0, 0);
    }

    #pragma unroll
    for (int mt = 0; mt < TM; ++mt) {
        #pragma unroll
        for (int nt = 0; nt < TN; ++nt) {
            const int gcol = col0 + wn * WN + nt * 16 + r;
            #pragma unroll
            for (int j = 0; j < 4; ++j) {
                const int grow = row0 + wm * WM + mt * 16 + q * 4 + j;
                if (grow < M) {
                    if (OUTBF16)
                        ((unsigned short*)Cv)[(size_t)grow * Ncols + gcol] = f2bf(acc[mt][nt][j]);
                    else
                        ((float*)Cv)[(size_t)grow * Ncols + gcol] = acc[mt][nt][j];
                }
            }
        }
    }
}

__global__ __launch_bounds__(256) void cast_f32_bf16(const float* __restrict__ in,
                                                     unsigned short* __restrict__ out,
                                                     long n4) {
    const long i = ((long)blockIdx.x * 256 + threadIdx.x);
    if (i < n4) {
        const float4 v = ((const float4*)in)[i];
        ushort4 o;
        o.x = f2bf(v.x); o.y = f2bf(v.y); o.z = f2bf(v.z); o.w = f2bf(v.w);
        ((ushort4*)out)[i] = o;
    }
}

// in: K x N fp32 -> out: N x K bf16 (transpose + cast); small matrices only.
__global__ __launch_bounds__(256) void transpose_cast(const float* __restrict__ in,
                                                      unsigned short* __restrict__ out,
                                                      int K, int N) {
    const int idx = blockIdx.x * 256 + threadIdx.x;
    if (idx < K * N) {
        const int k = idx / N, n = idx % N;
        out[(size_t)n * K + k] = f2bf(in[idx]);
    }
}

// ---- CSR build ----
__global__ __launch_bounds__(256) void hist_rows(const int* __restrict__ rows,
                                                 int* __restrict__ cnt, int E) {
    const int i = blockIdx.x * 256 + threadIdx.x;
    if (i < E) atomicAdd(&cnt[rows[i]], 1);
}

__global__ __launch_bounds__(256) void scan_pass1(const int* __restrict__ in,
                                                  int* __restrict__ out,
                                                  int* __restrict__ bsum, int n) {
    const int t = threadIdx.x;
    const int base = blockIdx.x * SCAN_CHUNK + t * 8;
    int v[8];
    int s = 0;
    #pragma unroll
    for (int i = 0; i < 8; ++i) {
        const int idx = base + i;
        v[i] = (idx < n) ? in[idx] : 0;
        s += v[i];
    }
    const int lane = t & 63;
    const int wid = t >> 6;
    int incl = s;
    #pragma unroll
    for (int o = 1; o < 64; o <<= 1) {
        int y = __shfl_up(incl, o);
        if (lane >= o) incl += y;
    }
    __shared__ int wsum[4];
    if (lane == 63) wsum[wid] = incl;
    __syncthreads();
    int woff = 0;
    for (int ww = 0; ww < wid; ++ww) woff += wsum[ww];
    int run = woff + incl - s;
    #pragma unroll
    for (int i = 0; i < 8; ++i) {
        const int idx = base + i;
        if (idx < n) out[idx] = run;
        run += v[i];
    }
    if (t == 255) bsum[blockIdx.x] = woff + incl;
}

__global__ void scan_pass2(int* __restrict__ bsum, int nb) {
    const int t = threadIdx.x;  // 64
    int carry = 0;
    for (int start = 0; start < nb; start += 64) {
        const int i = start + t;
        int v = (i < nb) ? bsum[i] : 0;
        int incl = v;
        #pragma unroll
        for (int o = 1; o < 64; o <<= 1) {
            int y = __shfl_up(incl, o);
            if (t >= o) incl += y;
        }
        if (i < nb) bsum[i] = carry + incl - v;
        carry += __shfl(incl, 63);
    }
}

__global__ __launch_bounds__(256) void scan_pass3(int* __restrict__ out,
                                                  const int* __restrict__ bsum, int n) {
    const int i = blockIdx.x * 256 + threadIdx.x;
    if (i < n) out[i] += bsum[i / SCAN_CHUNK];
}

__global__ __launch_bounds__(256) void scatter_edges(const int* __restrict__ rows,
                                                     const int* __restrict__ cols,
                                                     const float* __restrict__ vals,
                                                     const int* __restrict__ rs,
                                                     int* __restrict__ cursor,
                                                     int2* __restrict__ edges, int E) {
    const int e = blockIdx.x * 256 + threadIdx.x;
    if (e >= E) return;
    const int r = rows[e];
    const int pos = rs[r] + atomicAdd(&cursor[r], 1);
    edges[pos] = make_int2(cols[e], __float_as_int(vals[e]));
}

// ---- CSR spmm ----
// F=256 (bf16 X), fused bias+relu, bf16 out.
__global__ __launch_bounds__(256) void spmm_csr256_relu(const int2* __restrict__ edges,
                                                        const int* __restrict__ rs,
                                                        const unsigned short* __restrict__ X,
                                                        const float* __restrict__ bias,
                                                        unsigned short* __restrict__ Y, int N) {
    const int row = blockIdx.x * 4 + (threadIdx.x >> 6);
    if (row >= N) return;
    const int lane = threadIdx.x & 63;
    const int s = rs[row], e = rs[row + 1];
    float a0 = 0.f, a1 = 0.f, a2 = 0.f, a3 = 0.f;
    int i = s;
    for (; i + 1 < e; i += 2) {
        const int2 e0 = edges[i];
        const int2 e1 = edges[i + 1];
        const ushort4 x0 = ((const ushort4*)(X + (size_t)e0.x * 256))[lane];
        const ushort4 x1 = ((const ushort4*)(X + (size_t)e1.x * 256))[lane];
        const float v0 = __int_as_float(e0.y);
        const float v1 = __int_as_float(e1.y);
        a0 += v0 * bf2f(x0.x) + v1 * bf2f(x1.x);
        a1 += v0 * bf2f(x0.y) + v1 * bf2f(x1.y);
        a2 += v0 * bf2f(x0.z) + v1 * bf2f(x1.z);
        a3 += v0 * bf2f(x0.w) + v1 * bf2f(x1.w);
    }
    if (i < e) {
        const int2 e0 = edges[i];
        const ushort4 x0 = ((const ushort4*)(X + (size_t)e0.x * 256))[lane];
        const float v0 = __int_as_float(e0.y);
        a0 += v0 * bf2f(x0.x);
        a1 += v0 * bf2f(x0.y);
        a2 += v0 * bf2f(x0.z);
        a3 += v0 * bf2f(x0.w);
    }
    const float4 bb = ((const float4*)bias)[lane];
    ushort4 o;
    o.x = f2bf(fmaxf(a0 + bb.x, 0.f));
    o.y = f2bf(fmaxf(a1 + bb.y, 0.f));
    o.z = f2bf(fmaxf(a2 + bb.z, 0.f));
    o.w = f2bf(fmaxf(a3 + bb.w, 0.f));
    ((ushort4*)(Y + (size_t)row * 256))[lane] = o;
}

// F=64 (fp32 X), fused bias + log_softmax.
__global__ __launch_bounds__(256) void spmm_csr64_lsm(const int2* __restrict__ edges,
                                                      const int* __restrict__ rs,
                                                      const float* __restrict__ X,
                                                      const float* __restrict__ bias,
                                                      float* __restrict__ out, int N) {
    const int row = blockIdx.x * 4 + (threadIdx.x >> 6);
    if (row >= N) return;
    const int lane = threadIdx.x & 63;
    const int s = rs[row], e = rs[row + 1];
    float acc = 0.f;
    int i = s;
    for (; i + 1 < e; i += 2) {
        const int2 e0 = edges[i];
        const int2 e1 = edges[i + 1];
        acc += __int_as_float(e0.y) * X[(size_t)e0.x * 64 + lane]
             + __int_as_float(e1.y) * X[(size_t)e1.x * 64 + lane];
    }
    if (i < e) {
        const int2 e0 = edges[i];
        acc += __int_as_float(e0.y) * X[(size_t)e0.x * 64 + lane];
    }
    float v = acc + bias[lane];
    float m = v;
    #pragma unroll
    for (int o = 32; o; o >>= 1) m = fmaxf(m, __shfl_xor(m, o));
    const float ex = __expf(v - m);
    float ssum = ex;
    #pragma unroll
    for (int o = 32; o; o >>= 1) ssum += __shfl_xor(ssum, o);
    out[(size_t)row * 64 + lane] = v - m - __logf(ssum);
}

extern "C" void kernel_launch(void* const* d_in, const int* in_sizes, int n_in,
                              void* d_out, int out_size, void* d_ws, size_t ws_size,
                              hipStream_t stream) {
    const float* x    = (const float*)d_in[0];
    const int*   erow = (const int*)d_in[1];
    const int*   ecol = (const int*)d_in[2];
    const float* eval = (const float*)d_in[3];
    const float* W1   = (const float*)d_in[4];
    const float* b1   = (const float*)d_in[5];
    const float* W2   = (const float*)d_in[6];
    const float* b2   = (const float*)d_in[7];
    float* out = (float*)d_out;

    const int E      = in_sizes[1];
    const int nhid   = in_sizes[5];              // 256
    const int nclass = in_sizes[7];              // 64
    const int nfeat  = in_sizes[4] / nhid;       // 512
    const int N      = in_sizes[0] / nfeat;      // 100000

    // workspace layout (~180 MB, aliased regions noted)
    char* w = (char*)d_ws;
    unsigned short* xb  = (unsigned short*)w;     // N*nfeat bf16 (102.4 MB)
    unsigned short* h1b = (unsigned short*)w;     // aliases xb after gemm1 (N*nhid bf16)
    w += (size_t)N * nfeat * 2;
    unsigned short* h0b = (unsigned short*)w;     // N*nhid bf16 (51.2 MB)
    float* h2 = (float*)h0b;                      // aliases h0b after spmm1 (N*nclass fp32)
    w += (size_t)N * nhid * 2;
    int2* edges = (int2*)w;                       w += (size_t)E * 8;
    int* rs = (int*)w;                            w += (size_t)(N + 1) * 4;
    int* cursor = (int*)w;                        w += (size_t)N * 4;
    int* bsum = (int*)w;                          w += 64 * 4;
    unsigned short* W1T = (unsigned short*)w;     w += (size_t)nfeat * nhid * 2;
    unsigned short* W2T = (unsigned short*)w;     w += (size_t)nhid * nclass * 2;

    const int nScan = N + 1;
    const int nbScan = (nScan + SCAN_CHUNK - 1) / SCAN_CHUNK;

    hipMemsetAsync(rs, 0, (size_t)(N + 1) * sizeof(int), stream);
    hipMemsetAsync(cursor, 0, (size_t)N * sizeof(int), stream);

    // CSR build (shared by both spmm layers)
    hist_rows<<<(E + 255) / 256, 256, 0, stream>>>(erow, rs, E);
    scan_pass1<<<nbScan, 256, 0, stream>>>(rs, rs, bsum, nScan);
    scan_pass2<<<1, 64, 0, stream>>>(bsum, nbScan);
    scan_pass3<<<(nScan + 255) / 256, 256, 0, stream>>>(rs, bsum, nScan);
    scatter_edges<<<(E + 255) / 256, 256, 0, stream>>>(erow, ecol, eval, rs, cursor, edges, E);

    // casts
    const long n4 = (long)N * nfeat / 4;
    cast_f32_bf16<<<(int)((n4 + 255) / 256), 256, 0, stream>>>(x, xb, n4);
    transpose_cast<<<(nfeat * nhid + 255) / 256, 256, 0, stream>>>(W1, W1T, nfeat, nhid);
    transpose_cast<<<(nhid * nclass + 255) / 256, 256, 0, stream>>>(W2, W2T, nhid, nclass);

    // layer 1: h0b = bf16(xb @ W1)
    dim3 g1((N + 127) / 128, nhid / 128);
    gemm_mfma<128, 128, true><<<g1, 256, 0, stream>>>(xb, W1T, h0b, N, nhid, nfeat);
    // h1b = bf16(relu(spmm(h0b) + b1))
    spmm_csr256_relu<<<(N + 3) / 4, 256, 0, stream>>>(edges, rs, h0b, b1, h1b, N);

    // layer 2: h2 = h1b @ W2 (fp32 out)
    dim3 g2((N + 127) / 128, nclass / 64);
    gemm_mfma<128, 64, false><<<g2, 256, 0, stream>>>(h1b, W2T, h2, N, nclass, nhid);
    // out = log_softmax(spmm(h2) + b2)
    spmm_csr64_lsm<<<(N + 3) / 4, 256, 0, stream>>>(edges, rs, h2, b2, out, N);
}

// Round 4
// 1050.800 us; speedup vs baseline: 11.4293x; 1.0436x over previous
//
#include <hip/hip_runtime.h>
#include <math.h>

#define SCAN_CHUNK 2048

typedef short bf16x8 __attribute__((ext_vector_type(8)));
typedef float f32x4 __attribute__((ext_vector_type(4)));

__device__ __forceinline__ float bf2f(unsigned short u) {
    return __uint_as_float(((unsigned)u) << 16);
}
__device__ __forceinline__ unsigned short f2bf(float f) {
    unsigned u = __float_as_uint(f);
    unsigned r = u + 0x7FFF + ((u >> 16) & 1);   // RNE
    return (unsigned short)(r >> 16);
}

#define GLD_LDS16(gp, lp)                                                     \
    __builtin_amdgcn_global_load_lds(                                         \
        (const __attribute__((address_space(1))) void*)(gp),                  \
        (__attribute__((address_space(3))) void*)(lp), 16, 0, 0)

// C[M,Ncols] = A[M,K](bf16) @ BT[Ncols,K](bf16)^T, fp32 acc via MFMA.
// Block tile BM x BN, 4 waves in 2x2; requires Ncols % BN == 0.
template <int BM, int BN, bool OUTBF16>
__global__ __launch_bounds__(256) void gemm_mfma(const unsigned short* __restrict__ A,
                                                 const unsigned short* __restrict__ BT,
                                                 void* __restrict__ Cv,
                                                 int M, int Ncols, int K) {
    constexpr int WM = BM / 2, WN = BN / 2, TM = WM / 16, TN = WN / 16;
    __shared__ unsigned short Al[BM * 32];
    __shared__ unsigned short Bl[BN * 32];

    const int tid = threadIdx.x;
    const int w = tid >> 6, lane = tid & 63;
    const int wm = w >> 1, wn = w & 1;
    const int row0 = blockIdx.x * BM, col0 = blockIdx.y * BN;
    const int q = lane >> 4, r = lane & 15;

    f32x4 acc[TM][TN];
    #pragma unroll
    for (int mt = 0; mt < TM; ++mt)
        #pragma unroll
        for (int nt = 0; nt < TN; ++nt) {
            f32x4 z = {0.f, 0.f, 0.f, 0.f};
            acc[mt][nt] = z;
        }

    for (int k0 = 0; k0 < K; k0 += 32) {
        __syncthreads();
        // stage A tile: BM rows x 32 k (64 B/row = 4 x 16B chunks)
        #pragma unroll
        for (int i = 0; i < BM / 64; ++i) {
            const int idx = i * 256 + tid;
            const int arow = idx >> 2, ch = idx & 3;
            int grow = row0 + arow;
            if (grow >= M) grow = M - 1;
            GLD_LDS16(A + (size_t)grow * K + k0 + ch * 8,
                      Al + (size_t)(i * 256 + w * 64) * 8);
        }
        // stage BT tile: BN rows x 32 k
        #pragma unroll
        for (int i = 0; i < BN / 64; ++i) {
            const int idx = i * 256 + tid;
            const int brow = idx >> 2, ch = idx & 3;
            GLD_LDS16(BT + (size_t)(col0 + brow) * K + k0 + ch * 8,
                      Bl + (size_t)(i * 256 + w * 64) * 8);
        }
        asm volatile("s_waitcnt vmcnt(0)" ::: "memory");
        __syncthreads();

        bf16x8 af[TM], bfr[TN];
        #pragma unroll
        for (int mt = 0; mt < TM; ++mt)
            af[mt] = *(const bf16x8*)&Al[(wm * WM + mt * 16 + r) * 32 + q * 8];
        #pragma unroll
        for (int nt = 0; nt < TN; ++nt)
            bfr[nt] = *(const bf16x8*)&Bl[(wn * WN + nt * 16 + r) * 32 + q * 8];
        #pragma unroll
        for (int mt = 0; mt < TM; ++mt)
            #pragma unroll
            for (int nt = 0; nt < TN; ++nt)
                acc[mt][nt] = __builtin_amdgcn_mfma_f32_16x16x32_bf16(
                    af[mt], bfr[nt], acc[mt][nt], 0, 0, 0);
    }

    #pragma unroll
    for (int mt = 0; mt < TM; ++mt) {
        #pragma unroll
        for (int nt = 0; nt < TN; ++nt) {
            const int gcol = col0 + wn * WN + nt * 16 + r;
            #pragma unroll
            for (int j = 0; j < 4; ++j) {
                const int grow = row0 + wm * WM + mt * 16 + q * 4 + j;
                if (grow < M) {
                    if (OUTBF16)
                        ((unsigned short*)Cv)[(size_t)grow * Ncols + gcol] = f2bf(acc[mt][nt][j]);
                    else
                        ((float*)Cv)[(size_t)grow * Ncols + gcol] = acc[mt][nt][j];
                }
            }
        }
    }
}

__global__ __launch_bounds__(256) void cast_f32_bf16(const float* __restrict__ in,
                                                     unsigned short* __restrict__ out,
                                                     long n4) {
    const long i = ((long)blockIdx.x * 256 + threadIdx.x);
    if (i < n4) {
        const float4 v = ((const float4*)in)[i];
        ushort4 o;
        o.x = f2bf(v.x); o.y = f2bf(v.y); o.z = f2bf(v.z); o.w = f2bf(v.w);
        ((ushort4*)out)[i] = o;
    }
}

// in: K x N fp32 -> out: N x K bf16 (transpose + cast); small matrices only.
__global__ __launch_bounds__(256) void transpose_cast(const float* __restrict__ in,
                                                      unsigned short* __restrict__ out,
                                                      int K, int N) {
    const int idx = blockIdx.x * 256 + threadIdx.x;
    if (idx < K * N) {
        const int k = idx / N, n = idx % N;
        out[(size_t)n * K + k] = f2bf(in[idx]);
    }
}

// ---- CSR build ----
__global__ __launch_bounds__(256) void hist_rows(const int* __restrict__ rows,
                                                 int* __restrict__ cnt, int E) {
    const int i = blockIdx.x * 256 + threadIdx.x;
    if (i < E) atomicAdd(&cnt[rows[i]], 1);
}

__global__ __launch_bounds__(256) void scan_pass1(const int* __restrict__ in,
                                                  int* __restrict__ out,
                                                  int* __restrict__ bsum, int n) {
    const int t = threadIdx.x;
    const int base = blockIdx.x * SCAN_CHUNK + t * 8;
    int v[8];
    int s = 0;
    #pragma unroll
    for (int i = 0; i < 8; ++i) {
        const int idx = base + i;
        v[i] = (idx < n) ? in[idx] : 0;
        s += v[i];
    }
    const int lane = t & 63;
    const int wid = t >> 6;
    int incl = s;
    #pragma unroll
    for (int o = 1; o < 64; o <<= 1) {
        int y = __shfl_up(incl, o);
        if (lane >= o) incl += y;
    }
    __shared__ int wsum[4];
    if (lane == 63) wsum[wid] = incl;
    __syncthreads();
    int woff = 0;
    for (int ww = 0; ww < wid; ++ww) woff += wsum[ww];
    int run = woff + incl - s;
    #pragma unroll
    for (int i = 0; i < 8; ++i) {
        const int idx = base + i;
        if (idx < n) out[idx] = run;
        run += v[i];
    }
    if (t == 255) bsum[blockIdx.x] = woff + incl;
}

__global__ void scan_pass2(int* __restrict__ bsum, int nb) {
    const int t = threadIdx.x;  // 64
    int carry = 0;
    for (int start = 0; start < nb; start += 64) {
        const int i = start + t;
        int v = (i < nb) ? bsum[i] : 0;
        int incl = v;
        #pragma unroll
        for (int o = 1; o < 64; o <<= 1) {
            int y = __shfl_up(incl, o);
            if (t >= o) incl += y;
        }
        if (i < nb) bsum[i] = carry + incl - v;
        carry += __shfl(incl, 63);
    }
}

__global__ __launch_bounds__(256) void scan_pass3(int* __restrict__ out,
                                                  const int* __restrict__ bsum, int n) {
    const int i = blockIdx.x * 256 + threadIdx.x;
    if (i < n) out[i] += bsum[i / SCAN_CHUNK];
}

__global__ __launch_bounds__(256) void scatter_edges(const int* __restrict__ rows,
                                                     const int* __restrict__ cols,
                                                     const float* __restrict__ vals,
                                                     const int* __restrict__ rs,
                                                     int* __restrict__ cursor,
                                                     int2* __restrict__ edges, int E) {
    const int e = blockIdx.x * 256 + threadIdx.x;
    if (e >= E) return;
    const int r = rows[e];
    const int pos = rs[r] + atomicAdd(&cursor[r], 1);
    edges[pos] = make_int2(cols[e], __float_as_int(vals[e]));
}

// ---- CSR spmm ----
// F=256 (bf16 X), fused bias+relu, bf16 out. Unroll x4 for MLP.
__global__ __launch_bounds__(256) void spmm_csr256_relu(const int2* __restrict__ edges,
                                                        const int* __restrict__ rs,
                                                        const unsigned short* __restrict__ X,
                                                        const float* __restrict__ bias,
                                                        unsigned short* __restrict__ Y, int N) {
    const int row = blockIdx.x * 4 + (threadIdx.x >> 6);
    if (row >= N) return;
    const int lane = threadIdx.x & 63;
    const int s = rs[row], e = rs[row + 1];
    float a0 = 0.f, a1 = 0.f, a2 = 0.f, a3 = 0.f;
    int i = s;
    for (; i + 3 < e; i += 4) {
        const int2 e0 = edges[i];
        const int2 e1 = edges[i + 1];
        const int2 e2 = edges[i + 2];
        const int2 e3 = edges[i + 3];
        const ushort4 x0 = ((const ushort4*)(X + (size_t)e0.x * 256))[lane];
        const ushort4 x1 = ((const ushort4*)(X + (size_t)e1.x * 256))[lane];
        const ushort4 x2 = ((const ushort4*)(X + (size_t)e2.x * 256))[lane];
        const ushort4 x3 = ((const ushort4*)(X + (size_t)e3.x * 256))[lane];
        const float v0 = __int_as_float(e0.y);
        const float v1 = __int_as_float(e1.y);
        const float v2 = __int_as_float(e2.y);
        const float v3 = __int_as_float(e3.y);
        a0 += v0 * bf2f(x0.x) + v1 * bf2f(x1.x) + v2 * bf2f(x2.x) + v3 * bf2f(x3.x);
        a1 += v0 * bf2f(x0.y) + v1 * bf2f(x1.y) + v2 * bf2f(x2.y) + v3 * bf2f(x3.y);
        a2 += v0 * bf2f(x0.z) + v1 * bf2f(x1.z) + v2 * bf2f(x2.z) + v3 * bf2f(x3.z);
        a3 += v0 * bf2f(x0.w) + v1 * bf2f(x1.w) + v2 * bf2f(x2.w) + v3 * bf2f(x3.w);
    }
    for (; i < e; ++i) {
        const int2 e0 = edges[i];
        const ushort4 x0 = ((const ushort4*)(X + (size_t)e0.x * 256))[lane];
        const float v0 = __int_as_float(e0.y);
        a0 += v0 * bf2f(x0.x);
        a1 += v0 * bf2f(x0.y);
        a2 += v0 * bf2f(x0.z);
        a3 += v0 * bf2f(x0.w);
    }
    const float4 bb = ((const float4*)bias)[lane];
    ushort4 o;
    o.x = f2bf(fmaxf(a0 + bb.x, 0.f));
    o.y = f2bf(fmaxf(a1 + bb.y, 0.f));
    o.z = f2bf(fmaxf(a2 + bb.z, 0.f));
    o.w = f2bf(fmaxf(a3 + bb.w, 0.f));
    ((ushort4*)(Y + (size_t)row * 256))[lane] = o;
}

// F=64 (bf16 X), fused bias + log_softmax, fp32 out. Unroll x4.
__global__ __launch_bounds__(256) void spmm_csr64_lsm(const int2* __restrict__ edges,
                                                      const int* __restrict__ rs,
                                                      const unsigned short* __restrict__ X,
                                                      const float* __restrict__ bias,
                                                      float* __restrict__ out, int N) {
    const int row = blockIdx.x * 4 + (threadIdx.x >> 6);
    if (row >= N) return;
    const int lane = threadIdx.x & 63;
    const int s = rs[row], e = rs[row + 1];
    float acc = 0.f;
    int i = s;
    for (; i + 3 < e; i += 4) {
        const int2 e0 = edges[i];
        const int2 e1 = edges[i + 1];
        const int2 e2 = edges[i + 2];
        const int2 e3 = edges[i + 3];
        const float x0 = bf2f(X[(size_t)e0.x * 64 + lane]);
        const float x1 = bf2f(X[(size_t)e1.x * 64 + lane]);
        const float x2 = bf2f(X[(size_t)e2.x * 64 + lane]);
        const float x3 = bf2f(X[(size_t)e3.x * 64 + lane]);
        acc += __int_as_float(e0.y) * x0 + __int_as_float(e1.y) * x1
             + __int_as_float(e2.y) * x2 + __int_as_float(e3.y) * x3;
    }
    for (; i < e; ++i) {
        const int2 e0 = edges[i];
        acc += __int_as_float(e0.y) * bf2f(X[(size_t)e0.x * 64 + lane]);
    }
    float v = acc + bias[lane];
    float m = v;
    #pragma unroll
    for (int o = 32; o; o >>= 1) m = fmaxf(m, __shfl_xor(m, o));
    const float ex = __expf(v - m);
    float ssum = ex;
    #pragma unroll
    for (int o = 32; o; o >>= 1) ssum += __shfl_xor(ssum, o);
    out[(size_t)row * 64 + lane] = v - m - __logf(ssum);
}

extern "C" void kernel_launch(void* const* d_in, const int* in_sizes, int n_in,
                              void* d_out, int out_size, void* d_ws, size_t ws_size,
                              hipStream_t stream) {
    const float* x    = (const float*)d_in[0];
    const int*   erow = (const int*)d_in[1];
    const int*   ecol = (const int*)d_in[2];
    const float* eval = (const float*)d_in[3];
    const float* W1   = (const float*)d_in[4];
    const float* b1   = (const float*)d_in[5];
    const float* W2   = (const float*)d_in[6];
    const float* b2   = (const float*)d_in[7];
    float* out = (float*)d_out;

    const int E      = in_sizes[1];
    const int nhid   = in_sizes[5];              // 256
    const int nclass = in_sizes[7];              // 64
    const int nfeat  = in_sizes[4] / nhid;       // 512
    const int N      = in_sizes[0] / nfeat;      // 100000

    // workspace layout (~180 MB, aliased regions noted)
    char* w = (char*)d_ws;
    unsigned short* xb  = (unsigned short*)w;     // N*nfeat bf16 (102.4 MB)
    unsigned short* h1b = (unsigned short*)w;     // aliases xb after gemm1 (N*nhid bf16)
    w += (size_t)N * nfeat * 2;
    unsigned short* h0b = (unsigned short*)w;     // N*nhid bf16 (51.2 MB)
    unsigned short* h2b = h0b;                    // aliases h0b after spmm1 (N*nclass bf16)
    w += (size_t)N * nhid * 2;
    int2* edges = (int2*)w;                       w += (size_t)E * 8;
    int* rs = (int*)w;                            w += (size_t)(N + 1) * 4;
    int* cursor = (int*)w;                        w += (size_t)N * 4;
    int* bsum = (int*)w;                          w += 64 * 4;
    unsigned short* W1T = (unsigned short*)w;     w += (size_t)nfeat * nhid * 2;
    unsigned short* W2T = (unsigned short*)w;     w += (size_t)nhid * nclass * 2;

    const int nScan = N + 1;
    const int nbScan = (nScan + SCAN_CHUNK - 1) / SCAN_CHUNK;

    hipMemsetAsync(rs, 0, (size_t)(N + 1) * sizeof(int), stream);
    hipMemsetAsync(cursor, 0, (size_t)N * sizeof(int), stream);

    // CSR build (shared by both spmm layers)
    hist_rows<<<(E + 255) / 256, 256, 0, stream>>>(erow, rs, E);
    scan_pass1<<<nbScan, 256, 0, stream>>>(rs, rs, bsum, nScan);
    scan_pass2<<<1, 64, 0, stream>>>(bsum, nbScan);
    scan_pass3<<<(nScan + 255) / 256, 256, 0, stream>>>(rs, bsum, nScan);
    scatter_edges<<<(E + 255) / 256, 256, 0, stream>>>(erow, ecol, eval, rs, cursor, edges, E);

    // casts
    const long n4 = (long)N * nfeat / 4;
    cast_f32_bf16<<<(int)((n4 + 255) / 256), 256, 0, stream>>>(x, xb, n4);
    transpose_cast<<<(nfeat * nhid + 255) / 256, 256, 0, stream>>>(W1, W1T, nfeat, nhid);
    transpose_cast<<<(nhid * nclass + 255) / 256, 256, 0, stream>>>(W2, W2T, nhid, nclass);

    // layer 1: h0b = bf16(xb @ W1)  — BN=256 covers all of nhid, A read once
    dim3 g1((N + 127) / 128, nhid / 256);
    gemm_mfma<128, 256, true><<<g1, 256, 0, stream>>>(xb, W1T, h0b, N, nhid, nfeat);
    // h1b = bf16(relu(spmm(h0b) + b1))
    spmm_csr256_relu<<<(N + 3) / 4, 256, 0, stream>>>(edges, rs, h0b, b1, h1b, N);

    // layer 2: h2b = bf16(h1b @ W2)
    dim3 g2((N + 127) / 128, nclass / 64);
    gemm_mfma<128, 64, true><<<g2, 256, 0, stream>>>(h1b, W2T, h2b, N, nclass, nhid);
    // out = log_softmax(spmm(h2b) + b2)
    spmm_csr64_lsm<<<(N + 3) / 4, 256, 0, stream>>>(edges, rs, h2b, b2, out, N);
}

// Round 5
// 968.777 us; speedup vs baseline: 12.3970x; 1.0847x over previous
//
#include <hip/hip_runtime.h>
#include <math.h>

#define SCAN_CHUNK 2048

typedef short bf16x8 __attribute__((ext_vector_type(8)));
typedef float f32x4 __attribute__((ext_vector_type(4)));
typedef float f32x2 __attribute__((ext_vector_type(2)));

__device__ __forceinline__ float bf2f(unsigned short u) {
    return __uint_as_float(((unsigned)u) << 16);
}
__device__ __forceinline__ unsigned short f2bf(float f) {
    unsigned u = __float_as_uint(f);
    unsigned r = u + 0x7FFF + ((u >> 16) & 1);   // RNE
    return (unsigned short)(r >> 16);
}
__device__ __forceinline__ unsigned char f2fp8(float f) {
    const int p = __builtin_amdgcn_cvt_pk_fp8_f32(f, f, 0, false);
    return (unsigned char)(p & 0xff);
}

#define GLD_LDS16(gp, lp)                                                     \
    __builtin_amdgcn_global_load_lds(                                         \
        (const __attribute__((address_space(1))) void*)(gp),                  \
        (__attribute__((address_space(3))) void*)(lp), 16, 0, 0)

// C[M,Ncols] = A[M,K](bf16) @ BT[Ncols,K](bf16)^T, fp32 acc via MFMA.
// OUTMODE: 0 = fp32, 1 = bf16, 2 = fp8 e4m3.
template <int BM, int BN, int OUTMODE>
__global__ __launch_bounds__(256) void gemm_mfma(const unsigned short* __restrict__ A,
                                                 const unsigned short* __restrict__ BT,
                                                 void* __restrict__ Cv,
                                                 int M, int Ncols, int K) {
    constexpr int WM = BM / 2, WN = BN / 2, TM = WM / 16, TN = WN / 16;
    __shared__ unsigned short Al[BM * 32];
    __shared__ unsigned short Bl[BN * 32];

    const int tid = threadIdx.x;
    const int w = tid >> 6, lane = tid & 63;
    const int wm = w >> 1, wn = w & 1;
    const int row0 = blockIdx.x * BM, col0 = blockIdx.y * BN;
    const int q = lane >> 4, r = lane & 15;

    f32x4 acc[TM][TN];
    #pragma unroll
    for (int mt = 0; mt < TM; ++mt)
        #pragma unroll
        for (int nt = 0; nt < TN; ++nt) {
            f32x4 z = {0.f, 0.f, 0.f, 0.f};
            acc[mt][nt] = z;
        }

    for (int k0 = 0; k0 < K; k0 += 32) {
        __syncthreads();
        // stage A tile: BM rows x 32 k (64 B/row = 4 x 16B chunks)
        #pragma unroll
        for (int i = 0; i < BM / 64; ++i) {
            const int idx = i * 256 + tid;
            const int arow = idx >> 2, ch = idx & 3;
            int grow = row0 + arow;
            if (grow >= M) grow = M - 1;
            GLD_LDS16(A + (size_t)grow * K + k0 + ch * 8,
                      Al + (size_t)(i * 256 + w * 64) * 8);
        }
        // stage BT tile: BN rows x 32 k
        #pragma unroll
        for (int i = 0; i < BN / 64; ++i) {
            const int idx = i * 256 + tid;
            const int brow = idx >> 2, ch = idx & 3;
            GLD_LDS16(BT + (size_t)(col0 + brow) * K + k0 + ch * 8,
                      Bl + (size_t)(i * 256 + w * 64) * 8);
        }
        asm volatile("s_waitcnt vmcnt(0)" ::: "memory");
        __syncthreads();

        bf16x8 af[TM], bfr[TN];
        #pragma unroll
        for (int mt = 0; mt < TM; ++mt)
            af[mt] = *(const bf16x8*)&Al[(wm * WM + mt * 16 + r) * 32 + q * 8];
        #pragma unroll
        for (int nt = 0; nt < TN; ++nt)
            bfr[nt] = *(const bf16x8*)&Bl[(wn * WN + nt * 16 + r) * 32 + q * 8];
        #pragma unroll
        for (int mt = 0; mt < TM; ++mt)
            #pragma unroll
            for (int nt = 0; nt < TN; ++nt)
                acc[mt][nt] = __builtin_amdgcn_mfma_f32_16x16x32_bf16(
                    af[mt], bfr[nt], acc[mt][nt], 0, 0, 0);
    }

    #pragma unroll
    for (int mt = 0; mt < TM; ++mt) {
        #pragma unroll
        for (int nt = 0; nt < TN; ++nt) {
            const int gcol = col0 + wn * WN + nt * 16 + r;
            #pragma unroll
            for (int j = 0; j < 4; ++j) {
                const int grow = row0 + wm * WM + mt * 16 + q * 4 + j;
                if (grow < M) {
                    if (OUTMODE == 2)
                        ((unsigned char*)Cv)[(size_t)grow * Ncols + gcol] = f2fp8(acc[mt][nt][j]);
                    else if (OUTMODE == 1)
                        ((unsigned short*)Cv)[(size_t)grow * Ncols + gcol] = f2bf(acc[mt][nt][j]);
                    else
                        ((float*)Cv)[(size_t)grow * Ncols + gcol] = acc[mt][nt][j];
                }
            }
        }
    }
}

__global__ __launch_bounds__(256) void cast_f32_bf16(const float* __restrict__ in,
                                                     unsigned short* __restrict__ out,
                                                     long n4) {
    const long i = ((long)blockIdx.x * 256 + threadIdx.x);
    if (i < n4) {
        const float4 v = ((const float4*)in)[i];
        ushort4 o;
        o.x = f2bf(v.x); o.y = f2bf(v.y); o.z = f2bf(v.z); o.w = f2bf(v.w);
        ((ushort4*)out)[i] = o;
    }
}

// in: K x N fp32 -> out: N x K bf16 (transpose + cast); small matrices only.
__global__ __launch_bounds__(256) void transpose_cast(const float* __restrict__ in,
                                                      unsigned short* __restrict__ out,
                                                      int K, int N) {
    const int idx = blockIdx.x * 256 + threadIdx.x;
    if (idx < K * N) {
        const int k = idx / N, n = idx % N;
        out[(size_t)n * K + k] = f2bf(in[idx]);
    }
}

// ---- CSR build ----
__global__ __launch_bounds__(256) void hist_rows(const int* __restrict__ rows,
                                                 int* __restrict__ cnt, int E) {
    const int i = blockIdx.x * 256 + threadIdx.x;
    if (i < E) atomicAdd(&cnt[rows[i]], 1);
}

__global__ __launch_bounds__(256) void scan_pass1(const int* __restrict__ in,
                                                  int* __restrict__ out,
                                                  int* __restrict__ bsum, int n) {
    const int t = threadIdx.x;
    const int base = blockIdx.x * SCAN_CHUNK + t * 8;
    int v[8];
    int s = 0;
    #pragma unroll
    for (int i = 0; i < 8; ++i) {
        const int idx = base + i;
        v[i] = (idx < n) ? in[idx] : 0;
        s += v[i];
    }
    const int lane = t & 63;
    const int wid = t >> 6;
    int incl = s;
    #pragma unroll
    for (int o = 1; o < 64; o <<= 1) {
        int y = __shfl_up(incl, o);
        if (lane >= o) incl += y;
    }
    __shared__ int wsum[4];
    if (lane == 63) wsum[wid] = incl;
    __syncthreads();
    int woff = 0;
    for (int ww = 0; ww < wid; ++ww) woff += wsum[ww];
    int run = woff + incl - s;
    #pragma unroll
    for (int i = 0; i < 8; ++i) {
        const int idx = base + i;
        if (idx < n) out[idx] = run;
        run += v[i];
    }
    if (t == 255) bsum[blockIdx.x] = woff + incl;
}

__global__ void scan_pass2(int* __restrict__ bsum, int nb) {
    const int t = threadIdx.x;  // 64
    int carry = 0;
    for (int start = 0; start < nb; start += 64) {
        const int i = start + t;
        int v = (i < nb) ? bsum[i] : 0;
        int incl = v;
        #pragma unroll
        for (int o = 1; o < 64; o <<= 1) {
            int y = __shfl_up(incl, o);
            if (t >= o) incl += y;
        }
        if (i < nb) bsum[i] = carry + incl - v;
        carry += __shfl(incl, 63);
    }
}

__global__ __launch_bounds__(256) void scan_pass3(int* __restrict__ out,
                                                  const int* __restrict__ bsum, int n) {
    const int i = blockIdx.x * 256 + threadIdx.x;
    if (i < n) out[i] += bsum[i / SCAN_CHUNK];
}

__global__ __launch_bounds__(256) void scatter_edges(const int* __restrict__ rows,
                                                     const int* __restrict__ cols,
                                                     const float* __restrict__ vals,
                                                     const int* __restrict__ rs,
                                                     int* __restrict__ cursor,
                                                     int2* __restrict__ edges, int E) {
    const int e = blockIdx.x * 256 + threadIdx.x;
    if (e >= E) return;
    const int r = rows[e];
    const int pos = rs[r] + atomicAdd(&cursor[r], 1);
    edges[pos] = make_int2(cols[e], __float_as_int(vals[e]));
}

// ---- CSR spmm ----
// F=256 (fp8 X), fused bias+relu, bf16 out. Unroll x4 for MLP.
__global__ __launch_bounds__(256) void spmm_csr256_relu(const int2* __restrict__ edges,
                                                        const int* __restrict__ rs,
                                                        const unsigned char* __restrict__ X,
                                                        const float* __restrict__ bias,
                                                        unsigned short* __restrict__ Y, int N) {
    const int row = blockIdx.x * 4 + (threadIdx.x >> 6);
    if (row >= N) return;
    const int lane = threadIdx.x & 63;
    const int s = rs[row], e = rs[row + 1];
    float a0 = 0.f, a1 = 0.f, a2 = 0.f, a3 = 0.f;
    int i = s;
    for (; i + 3 < e; i += 4) {
        const int2 e0 = edges[i];
        const int2 e1 = edges[i + 1];
        const int2 e2 = edges[i + 2];
        const int2 e3 = edges[i + 3];
        const unsigned x0 = ((const unsigned*)(X + (size_t)e0.x * 256))[lane];
        const unsigned x1 = ((const unsigned*)(X + (size_t)e1.x * 256))[lane];
        const unsigned x2 = ((const unsigned*)(X + (size_t)e2.x * 256))[lane];
        const unsigned x3 = ((const unsigned*)(X + (size_t)e3.x * 256))[lane];
        const float v0 = __int_as_float(e0.y);
        const float v1 = __int_as_float(e1.y);
        const float v2 = __int_as_float(e2.y);
        const float v3 = __int_as_float(e3.y);
        const f32x2 l0 = __builtin_amdgcn_cvt_pk_f32_fp8(x0, false);
        const f32x2 h0 = __builtin_amdgcn_cvt_pk_f32_fp8(x0, true);
        const f32x2 l1 = __builtin_amdgcn_cvt_pk_f32_fp8(x1, false);
        const f32x2 h1 = __builtin_amdgcn_cvt_pk_f32_fp8(x1, true);
        const f32x2 l2 = __builtin_amdgcn_cvt_pk_f32_fp8(x2, false);
        const f32x2 h2 = __builtin_amdgcn_cvt_pk_f32_fp8(x2, true);
        const f32x2 l3 = __builtin_amdgcn_cvt_pk_f32_fp8(x3, false);
        const f32x2 h3 = __builtin_amdgcn_cvt_pk_f32_fp8(x3, true);
        a0 += v0 * l0.x + v1 * l1.x + v2 * l2.x + v3 * l3.x;
        a1 += v0 * l0.y + v1 * l1.y + v2 * l2.y + v3 * l3.y;
        a2 += v0 * h0.x + v1 * h1.x + v2 * h2.x + v3 * h3.x;
        a3 += v0 * h0.y + v1 * h1.y + v2 * h2.y + v3 * h3.y;
    }
    for (; i < e; ++i) {
        const int2 e0 = edges[i];
        const unsigned x0 = ((const unsigned*)(X + (size_t)e0.x * 256))[lane];
        const float v0 = __int_as_float(e0.y);
        const f32x2 l0 = __builtin_amdgcn_cvt_pk_f32_fp8(x0, false);
        const f32x2 h0 = __builtin_amdgcn_cvt_pk_f32_fp8(x0, true);
        a0 += v0 * l0.x;
        a1 += v0 * l0.y;
        a2 += v0 * h0.x;
        a3 += v0 * h0.y;
    }
    const float4 bb = ((const float4*)bias)[lane];
    ushort4 o;
    o.x = f2bf(fmaxf(a0 + bb.x, 0.f));
    o.y = f2bf(fmaxf(a1 + bb.y, 0.f));
    o.z = f2bf(fmaxf(a2 + bb.z, 0.f));
    o.w = f2bf(fmaxf(a3 + bb.w, 0.f));
    ((ushort4*)(Y + (size_t)row * 256))[lane] = o;
}

// F=64 (fp8 X), fused bias + log_softmax, fp32 out. Unroll x4.
__global__ __launch_bounds__(256) void spmm_csr64_lsm(const int2* __restrict__ edges,
                                                      const int* __restrict__ rs,
                                                      const unsigned char* __restrict__ X,
                                                      const float* __restrict__ bias,
                                                      float* __restrict__ out, int N) {
    const int row = blockIdx.x * 4 + (threadIdx.x >> 6);
    if (row >= N) return;
    const int lane = threadIdx.x & 63;
    const int s = rs[row], e = rs[row + 1];
    float acc = 0.f;
    int i = s;
    for (; i + 3 < e; i += 4) {
        const int2 e0 = edges[i];
        const int2 e1 = edges[i + 1];
        const int2 e2 = edges[i + 2];
        const int2 e3 = edges[i + 3];
        const int u0 = X[(size_t)e0.x * 64 + lane];
        const int u1 = X[(size_t)e1.x * 64 + lane];
        const int u2 = X[(size_t)e2.x * 64 + lane];
        const int u3 = X[(size_t)e3.x * 64 + lane];
        const float x0 = __builtin_amdgcn_cvt_f32_fp8(u0, 0);
        const float x1 = __builtin_amdgcn_cvt_f32_fp8(u1, 0);
        const float x2 = __builtin_amdgcn_cvt_f32_fp8(u2, 0);
        const float x3 = __builtin_amdgcn_cvt_f32_fp8(u3, 0);
        acc += __int_as_float(e0.y) * x0 + __int_as_float(e1.y) * x1
             + __int_as_float(e2.y) * x2 + __int_as_float(e3.y) * x3;
    }
    for (; i < e; ++i) {
        const int2 e0 = edges[i];
        const int u0 = X[(size_t)e0.x * 64 + lane];
        acc += __int_as_float(e0.y) * __builtin_amdgcn_cvt_f32_fp8(u0, 0);
    }
    float v = acc + bias[lane];
    float m = v;
    #pragma unroll
    for (int o = 32; o; o >>= 1) m = fmaxf(m, __shfl_xor(m, o));
    const float ex = __expf(v - m);
    float ssum = ex;
    #pragma unroll
    for (int o = 32; o; o >>= 1) ssum += __shfl_xor(ssum, o);
    out[(size_t)row * 64 + lane] = v - m - __logf(ssum);
}

extern "C" void kernel_launch(void* const* d_in, const int* in_sizes, int n_in,
                              void* d_out, int out_size, void* d_ws, size_t ws_size,
                              hipStream_t stream) {
    const float* x    = (const float*)d_in[0];
    const int*   erow = (const int*)d_in[1];
    const int*   ecol = (const int*)d_in[2];
    const float* eval = (const float*)d_in[3];
    const float* W1   = (const float*)d_in[4];
    const float* b1   = (const float*)d_in[5];
    const float* W2   = (const float*)d_in[6];
    const float* b2   = (const float*)d_in[7];
    float* out = (float*)d_out;

    const int E      = in_sizes[1];
    const int nhid   = in_sizes[5];              // 256
    const int nclass = in_sizes[7];              // 64
    const int nfeat  = in_sizes[4] / nhid;       // 512
    const int N      = in_sizes[0] / nfeat;      // 100000

    // workspace layout (~155 MB, aliased regions noted)
    char* w = (char*)d_ws;
    unsigned short* xb  = (unsigned short*)w;     // N*nfeat bf16 (102.4 MB)
    unsigned short* h1b = (unsigned short*)w;     // aliases xb after gemm1 (N*nhid bf16)
    w += (size_t)N * nfeat * 2;
    unsigned char* h0q = (unsigned char*)w;       // N*nhid fp8 (25.6 MB)
    unsigned char* h2q = h0q;                     // aliases h0q after spmm1 (N*nclass fp8)
    w += (size_t)N * nhid;
    int2* edges = (int2*)w;                       w += (size_t)E * 8;
    int* rs = (int*)w;                            w += (size_t)(N + 1) * 4;
    int* cursor = (int*)w;                        w += (size_t)N * 4;
    int* bsum = (int*)w;                          w += 64 * 4;
    unsigned short* W1T = (unsigned short*)w;     w += (size_t)nfeat * nhid * 2;
    unsigned short* W2T = (unsigned short*)w;     w += (size_t)nhid * nclass * 2;

    const int nScan = N + 1;
    const int nbScan = (nScan + SCAN_CHUNK - 1) / SCAN_CHUNK;

    hipMemsetAsync(rs, 0, (size_t)(N + 1) * sizeof(int), stream);
    hipMemsetAsync(cursor, 0, (size_t)N * sizeof(int), stream);

    // CSR build (shared by both spmm layers)
    hist_rows<<<(E + 255) / 256, 256, 0, stream>>>(erow, rs, E);
    scan_pass1<<<nbScan, 256, 0, stream>>>(rs, rs, bsum, nScan);
    scan_pass2<<<1, 64, 0, stream>>>(bsum, nbScan);
    scan_pass3<<<(nScan + 255) / 256, 256, 0, stream>>>(rs, bsum, nScan);
    scatter_edges<<<(E + 255) / 256, 256, 0, stream>>>(erow, ecol, eval, rs, cursor, edges, E);

    // casts
    const long n4 = (long)N * nfeat / 4;
    cast_f32_bf16<<<(int)((n4 + 255) / 256), 256, 0, stream>>>(x, xb, n4);
    transpose_cast<<<(nfeat * nhid + 255) / 256, 256, 0, stream>>>(W1, W1T, nfeat, nhid);
    transpose_cast<<<(nhid * nclass + 255) / 256, 256, 0, stream>>>(W2, W2T, nhid, nclass);

    // layer 1: h0q = fp8(xb @ W1)  — BN=256 covers all of nhid, A read once
    dim3 g1((N + 127) / 128, nhid / 256);
    gemm_mfma<128, 256, 2><<<g1, 256, 0, stream>>>(xb, W1T, h0q, N, nhid, nfeat);
    // h1b = bf16(relu(spmm(h0q) + b1))
    spmm_csr256_relu<<<(N + 3) / 4, 256, 0, stream>>>(edges, rs, h0q, b1, h1b, N);

    // layer 2: h2q = fp8(h1b @ W2)
    dim3 g2((N + 127) / 128, nclass / 64);
    gemm_mfma<128, 64, 2><<<g2, 256, 0, stream>>>(h1b, W2T, h2q, N, nclass, nhid);
    // out = log_softmax(spmm(h2q) + b2)
    spmm_csr64_lsm<<<(N + 3) / 4, 256, 0, stream>>>(edges, rs, h2q, b2, out, N);
}